// Round 1
// baseline (407.939 us; speedup 1.0000x reference)
//
#include <hip/hip_runtime.h>

typedef short bf16x8 __attribute__((ext_vector_type(8)));
typedef float f32x4 __attribute__((ext_vector_type(4)));
typedef unsigned short u16x8 __attribute__((ext_vector_type(8)));
typedef unsigned short u16x4 __attribute__((ext_vector_type(4)));

static __device__ __forceinline__ unsigned short f2bf(float f) {
  unsigned int x = __builtin_bit_cast(unsigned int, f);
  x += 0x7FFFu + ((x >> 16) & 1u);   // round-to-nearest-even
  return (unsigned short)(x >> 16);
}

// ---------------- fp32 -> bf16 convert (4 elems/thread) ----------------
__global__ __launch_bounds__(256) void cvt_bf16(const float* __restrict__ in,
                                                unsigned short* __restrict__ out) {
  int i = (blockIdx.x * 256 + threadIdx.x) * 4;
  float4 v = *(const float4*)(in + i);
  u16x4 o;
  o.x = f2bf(v.x); o.y = f2bf(v.y); o.z = f2bf(v.z); o.w = f2bf(v.w);
  *(u16x4*)(out + i) = o;
}

// ---------------- W [512k][512n] f32 -> WT [512n][512k] bf16 ----------------
__global__ __launch_bounds__(256) void wtrans(const float* __restrict__ W,
                                              unsigned short* __restrict__ WT) {
  __shared__ __align__(16) float T[64 * 68];
  const int k0 = blockIdx.x * 64, n0 = blockIdx.y * 64;
  const int tid = threadIdx.x;
#pragma unroll
  for (int i = 0; i < 4; ++i) {
    int chunk = i * 256 + tid;            // [0,1024)
    int row = chunk >> 4, fc = chunk & 15;
    *(float4*)(T + row * 68 + fc * 4) =
        *(const float4*)(W + (size_t)(k0 + row) * 512 + n0 + fc * 4);
  }
  __syncthreads();
#pragma unroll
  for (int i = 0; i < 2; ++i) {
    int chunk = i * 256 + tid;            // [0,512)
    int nr = chunk >> 3, kc = chunk & 7;
    u16x8 v;
#pragma unroll
    for (int j = 0; j < 8; ++j) v[j] = f2bf(T[(kc * 8 + j) * 68 + nr]);
    *(u16x8*)(WT + (size_t)(n0 + nr) * 512 + k0 + kc * 8) = v;
  }
}

// ---------------- TN GEMM: C[M,N] = A[M,K] * Bt[N,K]^T  (bf16 in, 128x128 tile) ----------------
template <int OUT_F32>
__global__ __launch_bounds__(256) void gemm_tn(const unsigned short* __restrict__ A,
                                               const unsigned short* __restrict__ Bt,
                                               unsigned short* __restrict__ Cb,
                                               float* __restrict__ Cf,
                                               int M, int N, int K) {
  __shared__ __align__(16) unsigned short Ash[128 * 32];
  __shared__ __align__(16) unsigned short Bsh[128 * 32];
  const int tid = threadIdx.x;
  const int wid = tid >> 6, lane = tid & 63, quad = lane >> 4, li = lane & 15;
  const int bm = blockIdx.x * 128, bn = blockIdx.y * 128;
  const int wm = (wid >> 1) * 64, wn = (wid & 1) * 64;
  f32x4 acc[4][4] = {};
  for (int k0 = 0; k0 < K; k0 += 32) {
    __syncthreads();
#pragma unroll
    for (int i = 0; i < 2; ++i) {
      int chunk = i * 256 + tid;          // [0,512): row=chunk>>2, kc=chunk&3
      int row = chunk >> 2, kc = chunk & 3;
      *(uint4*)(Ash + row * 32 + kc * 8) =
          *(const uint4*)(A + (size_t)(bm + row) * K + k0 + kc * 8);
      *(uint4*)(Bsh + row * 32 + kc * 8) =
          *(const uint4*)(Bt + (size_t)(bn + row) * K + k0 + kc * 8);
    }
    __syncthreads();
    bf16x8 af[4], bfr[4];
#pragma unroll
    for (int t = 0; t < 4; ++t) {
      af[t]  = *(const bf16x8*)(Ash + (wm + t * 16 + li) * 32 + quad * 8);
      bfr[t] = *(const bf16x8*)(Bsh + (wn + t * 16 + li) * 32 + quad * 8);
    }
#pragma unroll
    for (int mt = 0; mt < 4; ++mt)
#pragma unroll
      for (int nt = 0; nt < 4; ++nt)
        acc[mt][nt] = __builtin_amdgcn_mfma_f32_16x16x32_bf16(af[mt], bfr[nt], acc[mt][nt], 0, 0, 0);
  }
#pragma unroll
  for (int mt = 0; mt < 4; ++mt)
#pragma unroll
    for (int nt = 0; nt < 4; ++nt) {
      int r0 = bm + wm + mt * 16 + quad * 4;
      int c  = bn + wn + nt * 16 + li;
#pragma unroll
      for (int r = 0; r < 4; ++r) {
        float v = acc[mt][nt][r];
        if (OUT_F32) Cf[(size_t)(r0 + r) * N + c] = v;
        else         Cb[(size_t)(r0 + r) * N + c] = f2bf(v);
      }
    }
}

// ---------------- vh [B*L][512] -> vt [(b*8+h)*64+d][4096]  (per-head V^T) ----------------
__global__ __launch_bounds__(256) void vtrans(const unsigned short* __restrict__ vh,
                                              unsigned short* __restrict__ vt) {
  __shared__ __align__(16) unsigned short T[64 * 72];
  const int kt = blockIdx.x;      // key tile
  const int bh = blockIdx.y;      // b*8+h
  const int b = bh >> 3, h = bh & 7;
  const int tid = threadIdx.x;
#pragma unroll
  for (int i = 0; i < 2; ++i) {
    int chunk = i * 256 + tid;
    int row = chunk >> 3, c8 = chunk & 7;
    *(uint4*)(T + row * 72 + c8 * 8) =
        *(const uint4*)(vh + (size_t)(b * 4096 + kt * 64 + row) * 512 + h * 64 + c8 * 8);
  }
  __syncthreads();
#pragma unroll
  for (int i = 0; i < 2; ++i) {
    int chunk = i * 256 + tid;
    int dr = chunk >> 3, c8 = chunk & 7;
    u16x8 v;
#pragma unroll
    for (int j = 0; j < 8; ++j) v[j] = T[(c8 * 8 + j) * 72 + dr];
    *(u16x8*)(vt + (size_t)(bh * 64 + dr) * 4096 + kt * 64 + c8 * 8) = v;
  }
}

// ---------------- flash attention: one block = (b, h, 64 queries); 4 waves x 16 q ----------------
__global__ __launch_bounds__(256) void attn(const unsigned short* __restrict__ qh,
                                            const unsigned short* __restrict__ kh,
                                            const unsigned short* __restrict__ vt,
                                            const int* __restrict__ mask,
                                            unsigned short* __restrict__ obuf) {
  __shared__ __align__(16) unsigned short Ksh[64 * 72];   // [key][dim], pad 72
  __shared__ __align__(16) unsigned short Vsh[64 * 72];   // [dim][key], pad 72
  __shared__ __align__(16) unsigned short Psh[4][16 * 72];
  __shared__ float Msk[64];
  const int qt = blockIdx.x, h = blockIdx.y, b = blockIdx.z;
  const int tid = threadIdx.x;
  const int wid = tid >> 6, lane = tid & 63, quad = lane >> 4, li = lane & 15;
  const size_t tok0 = (size_t)b * 4096;

  // Q A-fragments: rows = qt*64 + wid*16 + li, k = quad*8 (+32)
  const unsigned short* qp = qh + (tok0 + qt * 64 + wid * 16 + li) * 512 + h * 64;
  bf16x8 aq0 = *(const bf16x8*)(qp + quad * 8);
  bf16x8 aq1 = *(const bf16x8*)(qp + 32 + quad * 8);

  float m_i[4], l_i[4];
  f32x4 accO[4] = {};
#pragma unroll
  for (int r = 0; r < 4; ++r) { m_i[r] = -1e30f; l_i[r] = 0.f; }
  const float scale = 0.125f;  // 1/sqrt(64)
  const unsigned short* kbase = kh + tok0 * 512 + h * 64;
  const unsigned short* vbase = vt + (size_t)(b * 8 + h) * 64 * 4096;

  for (int kt = 0; kt < 4096; kt += 64) {
    __syncthreads();
#pragma unroll
    for (int i = 0; i < 2; ++i) {
      int chunk = i * 256 + tid;
      int row = chunk >> 3, c8 = chunk & 7;
      *(uint4*)(Ksh + row * 72 + c8 * 8) =
          *(const uint4*)(kbase + (size_t)(kt + row) * 512 + c8 * 8);
      *(uint4*)(Vsh + row * 72 + c8 * 8) =
          *(const uint4*)(vbase + (size_t)row * 4096 + kt + c8 * 8);
    }
    if (tid < 64) Msk[tid] = mask[b * 4096 + kt + tid] ? 0.f : -1e30f;
    __syncthreads();

    // S = Q K^T  (rows=queries quad*4+r, cols=keys c*16+li)
    f32x4 s[4];
#pragma unroll
    for (int c = 0; c < 4; ++c) {
      bf16x8 bk0 = *(const bf16x8*)(Ksh + (c * 16 + li) * 72 + quad * 8);
      bf16x8 bk1 = *(const bf16x8*)(Ksh + (c * 16 + li) * 72 + 32 + quad * 8);
      f32x4 z = {};
      z = __builtin_amdgcn_mfma_f32_16x16x32_bf16(aq0, bk0, z, 0, 0, 0);
      z = __builtin_amdgcn_mfma_f32_16x16x32_bf16(aq1, bk1, z, 0, 0, 0);
      s[c] = z;
    }
#pragma unroll
    for (int c = 0; c < 4; ++c) {
      float bias = Msk[c * 16 + li];
#pragma unroll
      for (int r = 0; r < 4; ++r) s[c][r] = s[c][r] * scale + bias;
    }
    // online softmax: row stats via quad-local 16-lane shuffles
    float alpha[4], rs[4];
#pragma unroll
    for (int r = 0; r < 4; ++r) {
      float v = fmaxf(fmaxf(s[0][r], s[1][r]), fmaxf(s[2][r], s[3][r]));
#pragma unroll
      for (int off = 1; off < 16; off <<= 1) v = fmaxf(v, __shfl_xor(v, off));
      float mn = fmaxf(m_i[r], v);
      alpha[r] = __expf(m_i[r] - mn);
      m_i[r] = mn;
      rs[r] = 0.f;
    }
#pragma unroll
    for (int c = 0; c < 4; ++c)
#pragma unroll
      for (int r = 0; r < 4; ++r) {
        float p = __expf(s[c][r] - m_i[r]);
        s[c][r] = p;
        rs[r] += p;
      }
#pragma unroll
    for (int r = 0; r < 4; ++r) {
#pragma unroll
      for (int off = 1; off < 16; off <<= 1) rs[r] += __shfl_xor(rs[r], off);
      l_i[r] = l_i[r] * alpha[r] + rs[r];
    }
    // P: C-layout regs -> per-wave LDS -> A-layout frags
#pragma unroll
    for (int c = 0; c < 4; ++c)
#pragma unroll
      for (int r = 0; r < 4; ++r)
        Psh[wid][(quad * 4 + r) * 72 + c * 16 + li] = f2bf(s[c][r]);
#pragma unroll
    for (int dc = 0; dc < 4; ++dc)
#pragma unroll
      for (int r = 0; r < 4; ++r) accO[dc][r] *= alpha[r];
    bf16x8 p0 = *(const bf16x8*)(&Psh[wid][li * 72 + quad * 8]);
    bf16x8 p1 = *(const bf16x8*)(&Psh[wid][li * 72 + 32 + quad * 8]);
#pragma unroll
    for (int dc = 0; dc < 4; ++dc) {
      bf16x8 bv0 = *(const bf16x8*)(Vsh + (dc * 16 + li) * 72 + quad * 8);
      bf16x8 bv1 = *(const bf16x8*)(Vsh + (dc * 16 + li) * 72 + 32 + quad * 8);
      accO[dc] = __builtin_amdgcn_mfma_f32_16x16x32_bf16(p0, bv0, accO[dc], 0, 0, 0);
      accO[dc] = __builtin_amdgcn_mfma_f32_16x16x32_bf16(p1, bv1, accO[dc], 0, 0, 0);
    }
  }
  // epilogue: O /= l, store bf16 to [token][h*64+d]
#pragma unroll
  for (int dc = 0; dc < 4; ++dc)
#pragma unroll
    for (int r = 0; r < 4; ++r) {
      size_t row = tok0 + qt * 64 + wid * 16 + quad * 4 + r;
      obuf[row * 512 + h * 64 + dc * 16 + li] = f2bf(accO[dc][r] / l_i[r]);
    }
}

extern "C" void kernel_launch(void* const* d_in, const int* in_sizes, int n_in,
                              void* d_out, int out_size, void* d_ws, size_t ws_size,
                              hipStream_t stream) {
  const float* q  = (const float*)d_in[0];
  const float* k  = (const float*)d_in[1];
  const float* v  = (const float*)d_in[2];
  const int* mask = (const int*)d_in[3];
  const float* Wq = (const float*)d_in[4];
  const float* Wk = (const float*)d_in[5];
  const float* Wv = (const float*)d_in[6];
  const float* Wo = (const float*)d_in[7];
  float* out = (float*)d_out;

  char* ws = (char*)d_ws;
  const size_t SA = (size_t)8192 * 512 * 2;  // 8 MB per activation buffer
  unsigned short* qbf = (unsigned short*)(ws);
  unsigned short* kbf = (unsigned short*)(ws + SA);
  unsigned short* vbf = (unsigned short*)(ws + 2 * SA);
  unsigned short* qhb = (unsigned short*)(ws + 3 * SA);
  unsigned short* khb = (unsigned short*)(ws + 4 * SA);
  unsigned short* vhb = (unsigned short*)(ws + 5 * SA);
  unsigned short* wqT = (unsigned short*)(ws + 6 * SA);
  unsigned short* wkT = wqT + 512 * 512;
  unsigned short* wvT = wkT + 512 * 512;
  unsigned short* woT = wvT + 512 * 512;
  unsigned short* vtb = qbf;  // reuse: qbf dead after qh GEMM
  unsigned short* ob  = kbf;  // reuse: kbf dead after kh GEMM

  cvt_bf16<<<4096, 256, 0, stream>>>(q, qbf);
  cvt_bf16<<<4096, 256, 0, stream>>>(k, kbf);
  cvt_bf16<<<4096, 256, 0, stream>>>(v, vbf);
  dim3 wg(8, 8);
  wtrans<<<wg, 256, 0, stream>>>(Wq, wqT);
  wtrans<<<wg, 256, 0, stream>>>(Wk, wkT);
  wtrans<<<wg, 256, 0, stream>>>(Wv, wvT);
  wtrans<<<wg, 256, 0, stream>>>(Wo, woT);
  dim3 gg(64, 4);
  gemm_tn<0><<<gg, 256, 0, stream>>>(qbf, wqT, qhb, nullptr, 8192, 512, 512);
  gemm_tn<0><<<gg, 256, 0, stream>>>(kbf, wkT, khb, nullptr, 8192, 512, 512);
  gemm_tn<0><<<gg, 256, 0, stream>>>(vbf, wvT, vhb, nullptr, 8192, 512, 512);
  dim3 vg(64, 16);
  vtrans<<<vg, 256, 0, stream>>>(vhb, vtb);
  dim3 ag(64, 8, 2);
  attn<<<ag, 256, 0, stream>>>(qhb, khb, vtb, mask, ob);
  gemm_tn<1><<<gg, 256, 0, stream>>>(ob, woT, nullptr, out, 8192, 512, 512);
}

// Round 2
// 349.159 us; speedup vs baseline: 1.1683x; 1.1683x over previous
//
#include <hip/hip_runtime.h>

typedef short bf16x8 __attribute__((ext_vector_type(8)));
typedef float f32x4 __attribute__((ext_vector_type(4)));
typedef unsigned short u16x8 __attribute__((ext_vector_type(8)));

static __device__ __forceinline__ unsigned short f2bf(float f) {
  unsigned int x = __builtin_bit_cast(unsigned int, f);
  x += 0x7FFFu + ((x >> 16) & 1u);   // RNE
  return (unsigned short)(x >> 16);
}
// fast round-half-up pack of two floats' bf16 into one u32 (lo = a, hi = b)
static __device__ __forceinline__ unsigned int pk2bf(float a, float b) {
  unsigned int ia = __builtin_bit_cast(unsigned int, a) + 0x8000u;
  unsigned int ib = __builtin_bit_cast(unsigned int, b) + 0x8000u;
  return __builtin_amdgcn_perm(ib, ia, 0x07060302u);  // {ib_hi16, ia_hi16}
}

// ---------------- W [512k][512n] f32 -> WT [512n][512k] bf16 ----------------
__global__ __launch_bounds__(256) void wtrans(const float* __restrict__ W,
                                              unsigned short* __restrict__ WT) {
  __shared__ __align__(16) float T[64 * 68];
  const int k0 = blockIdx.x * 64, n0 = blockIdx.y * 64;
  const int tid = threadIdx.x;
#pragma unroll
  for (int i = 0; i < 4; ++i) {
    int chunk = i * 256 + tid;
    int row = chunk >> 4, fc = chunk & 15;
    *(float4*)(T + row * 68 + fc * 4) =
        *(const float4*)(W + (size_t)(k0 + row) * 512 + n0 + fc * 4);
  }
  __syncthreads();
#pragma unroll
  for (int i = 0; i < 2; ++i) {
    int chunk = i * 256 + tid;
    int nr = chunk >> 3, kc = chunk & 7;
    u16x8 v;
#pragma unroll
    for (int j = 0; j < 8; ++j) v[j] = f2bf(T[(kc * 8 + j) * 68 + nr]);
    *(u16x8*)(WT + (size_t)(n0 + nr) * 512 + k0 + kc * 8) = v;
  }
}

// ---------------- TN GEMM 64x64 tile, BK=64: C[M,N] = A[M,K] * Bt[N,K]^T ----------------
// A_F32: A is fp32 (converted to bf16 during staging). OUT_F32: write fp32 C, else bf16.
template <int A_F32, int OUT_F32>
__global__ __launch_bounds__(256) void gemm_tn(const float* __restrict__ Af,
                                               const unsigned short* __restrict__ Ab,
                                               const unsigned short* __restrict__ Bt,
                                               unsigned short* __restrict__ Cb,
                                               float* __restrict__ Cf,
                                               float scale, int M, int N, int K) {
  __shared__ __align__(16) unsigned short Ash[64 * 72];
  __shared__ __align__(16) unsigned short Bsh[64 * 72];
  const int tid = threadIdx.x;
  const int wid = tid >> 6, lane = tid & 63, quad = lane >> 4, li = lane & 15;
  const int bm = blockIdx.x * 64, bn = blockIdx.y * 64;
  const int wm = (wid >> 1) * 32, wn = (wid & 1) * 32;
  f32x4 acc[2][2] = {};
  for (int k0 = 0; k0 < K; k0 += 64) {
    __syncthreads();
    if (A_F32) {
#pragma unroll
      for (int i = 0; i < 4; ++i) {
        int chunk = i * 256 + tid;          // [0,1024)
        int row = chunk >> 4, c4 = chunk & 15;
        float4 v = *(const float4*)(Af + (size_t)(bm + row) * K + k0 + c4 * 4);
        uint2 pk;
        pk.x = pk2bf(v.x, v.y);
        pk.y = pk2bf(v.z, v.w);
        *(uint2*)(Ash + row * 72 + c4 * 4) = pk;
      }
    } else {
#pragma unroll
      for (int i = 0; i < 2; ++i) {
        int chunk = i * 256 + tid;          // [0,512)
        int row = chunk >> 3, c8 = chunk & 7;
        *(uint4*)(Ash + row * 72 + c8 * 8) =
            *(const uint4*)(Ab + (size_t)(bm + row) * K + k0 + c8 * 8);
      }
    }
#pragma unroll
    for (int i = 0; i < 2; ++i) {
      int chunk = i * 256 + tid;
      int row = chunk >> 3, c8 = chunk & 7;
      *(uint4*)(Bsh + row * 72 + c8 * 8) =
          *(const uint4*)(Bt + (size_t)(bn + row) * K + k0 + c8 * 8);
    }
    __syncthreads();
#pragma unroll
    for (int kk = 0; kk < 2; ++kk) {
      bf16x8 af[2], bfr[2];
#pragma unroll
      for (int t = 0; t < 2; ++t) {
        af[t]  = *(const bf16x8*)(Ash + (wm + t * 16 + li) * 72 + kk * 32 + quad * 8);
        bfr[t] = *(const bf16x8*)(Bsh + (wn + t * 16 + li) * 72 + kk * 32 + quad * 8);
      }
#pragma unroll
      for (int mt = 0; mt < 2; ++mt)
#pragma unroll
        for (int nt = 0; nt < 2; ++nt)
          acc[mt][nt] = __builtin_amdgcn_mfma_f32_16x16x32_bf16(af[mt], bfr[nt], acc[mt][nt], 0, 0, 0);
    }
  }
#pragma unroll
  for (int mt = 0; mt < 2; ++mt)
#pragma unroll
    for (int nt = 0; nt < 2; ++nt) {
      int r0 = bm + wm + mt * 16 + quad * 4;
      int c  = bn + wn + nt * 16 + li;
#pragma unroll
      for (int r = 0; r < 4; ++r) {
        float v = acc[mt][nt][r] * scale;
        if (OUT_F32) Cf[(size_t)(r0 + r) * N + c] = v;
        else         Cb[(size_t)(r0 + r) * N + c] = f2bf(v);
      }
    }
}

// ---------------- vh [B*L][512] -> vt [(b*8+h)*64+d][4096]  (per-head V^T) ----------------
__global__ __launch_bounds__(256) void vtrans(const unsigned short* __restrict__ vh,
                                              unsigned short* __restrict__ vt) {
  __shared__ __align__(16) unsigned short T[64 * 72];
  const int kt = blockIdx.x;      // key tile
  const int bh = blockIdx.y;      // b*8+h
  const int b = bh >> 3, h = bh & 7;
  const int tid = threadIdx.x;
#pragma unroll
  for (int i = 0; i < 2; ++i) {
    int chunk = i * 256 + tid;
    int row = chunk >> 3, c8 = chunk & 7;
    *(uint4*)(T + row * 72 + c8 * 8) =
        *(const uint4*)(vh + (size_t)(b * 4096 + kt * 64 + row) * 512 + h * 64 + c8 * 8);
  }
  __syncthreads();
#pragma unroll
  for (int i = 0; i < 2; ++i) {
    int chunk = i * 256 + tid;
    int dr = chunk >> 3, c8 = chunk & 7;
    u16x8 v;
#pragma unroll
    for (int j = 0; j < 8; ++j) v[j] = T[(c8 * 8 + j) * 72 + dr];
    *(u16x8*)(vt + (size_t)(bh * 64 + dr) * 4096 + kt * 64 + c8 * 8) = v;
  }
}

// ---------------- flash attention, S^T form: block = (qt, h, b), 4 waves x 16 q ----------------
// qh is PRE-SCALED by 1/sqrt(64) * log2(e) in the Q projection epilogue; exp2 domain throughout.
__global__ __launch_bounds__(256) void attn(const unsigned short* __restrict__ qh,
                                            const unsigned short* __restrict__ kh,
                                            const unsigned short* __restrict__ vt,
                                            const int* __restrict__ mask,
                                            unsigned short* __restrict__ obuf) {
  __shared__ __align__(16) unsigned short Ksh[64 * 72];   // [key][dim]
  __shared__ __align__(16) unsigned short Vsh[64 * 72];   // [dim][key]
  __shared__ __align__(16) unsigned short Psh[4][16 * 72];// per-wave P [q][k]
  __shared__ float Msk[64];
  __shared__ int MskOkSh;
  const int qt = blockIdx.x, h = blockIdx.y, b = blockIdx.z;
  const int tid = threadIdx.x;
  const int wid = tid >> 6, lane = tid & 63, quad = lane >> 4, li = lane & 15;
  const size_t tok0 = (size_t)b * 4096;

  // Q as B-operand: lane holds Q[qbase+li][d = quad*8+j]
  const unsigned short* qp = qh + (tok0 + qt * 64 + wid * 16 + li) * 512 + h * 64;
  bf16x8 bq0 = *(const bf16x8*)(qp + quad * 8);
  bf16x8 bq1 = *(const bf16x8*)(qp + 32 + quad * 8);

  float m_i = -1e30f, l_i = 0.f;
  f32x4 accO[4] = {};
  const unsigned short* kbase = kh + tok0 * 512 + h * 64;
  const unsigned short* vbase = vt + (size_t)(b * 8 + h) * 64 * 4096;
  unsigned short* Pw = &Psh[wid][0];

  for (int kt = 0; kt < 4096; kt += 64) {
    __syncthreads();
#pragma unroll
    for (int i = 0; i < 2; ++i) {
      int chunk = i * 256 + tid;
      int row = chunk >> 3, c8 = chunk & 7;
      *(uint4*)(Ksh + row * 72 + c8 * 8) =
          *(const uint4*)(kbase + (size_t)(kt + row) * 512 + c8 * 8);
      *(uint4*)(Vsh + row * 72 + c8 * 8) =
          *(const uint4*)(vbase + (size_t)row * 4096 + kt + c8 * 8);
    }
    if (tid < 64) {
      int mv = mask[b * 4096 + kt + tid];
      Msk[tid] = mv ? 0.f : -1e30f;
      unsigned long long bal = __ballot(mv != 0);
      if (tid == 0) MskOkSh = (bal + 1ull == 0ull);
    }
    __syncthreads();

    // S^T = K Q^T: lane holds query q=li, keys kb*16 + quad*4 + r
    f32x4 s[4];
#pragma unroll
    for (int kb = 0; kb < 4; ++kb) {
      bf16x8 ak0 = *(const bf16x8*)(Ksh + (kb * 16 + li) * 72 + quad * 8);
      bf16x8 ak1 = *(const bf16x8*)(Ksh + (kb * 16 + li) * 72 + 32 + quad * 8);
      f32x4 z = {};
      z = __builtin_amdgcn_mfma_f32_16x16x32_bf16(ak0, bq0, z, 0, 0, 0);
      z = __builtin_amdgcn_mfma_f32_16x16x32_bf16(ak1, bq1, z, 0, 0, 0);
      s[kb] = z;
    }
    if (!MskOkSh) {
#pragma unroll
      for (int kb = 0; kb < 4; ++kb)
#pragma unroll
        for (int r = 0; r < 4; ++r) s[kb][r] += Msk[kb * 16 + quad * 4 + r];
    }
    // online softmax over keys (per-lane query)
    float mx = s[0][0];
#pragma unroll
    for (int kb = 0; kb < 4; ++kb)
#pragma unroll
      for (int r = 0; r < 4; ++r) mx = fmaxf(mx, s[kb][r]);
    mx = fmaxf(mx, __shfl_xor(mx, 16));
    mx = fmaxf(mx, __shfl_xor(mx, 32));
    float mn = fmaxf(m_i, mx);
    float alpha = __builtin_amdgcn_exp2f(m_i - mn);
    m_i = mn;
    float rs = 0.f;
#pragma unroll
    for (int kb = 0; kb < 4; ++kb)
#pragma unroll
      for (int r = 0; r < 4; ++r) {
        float p = __builtin_amdgcn_exp2f(s[kb][r] - mn);
        s[kb][r] = p;
        rs += p;
      }
    rs += __shfl_xor(rs, 16);
    rs += __shfl_xor(rs, 32);
    l_i = l_i * alpha + rs;
    // P[q=li][k] bf16 -> per-wave LDS (4x ds_write_b64)
#pragma unroll
    for (int kb = 0; kb < 4; ++kb) {
      uint2 pk;
      pk.x = pk2bf(s[kb][0], s[kb][1]);
      pk.y = pk2bf(s[kb][2], s[kb][3]);
      *(uint2*)(Pw + li * 72 + kb * 16 + quad * 4) = pk;
    }
    // rescale O rows (rows are queries quad*4+r)
    float av0 = __shfl(alpha, quad * 4 + 0);
    float av1 = __shfl(alpha, quad * 4 + 1);
    float av2 = __shfl(alpha, quad * 4 + 2);
    float av3 = __shfl(alpha, quad * 4 + 3);
#pragma unroll
    for (int dc = 0; dc < 4; ++dc) {
      accO[dc][0] *= av0; accO[dc][1] *= av1;
      accO[dc][2] *= av2; accO[dc][3] *= av3;
    }
    // O += P V  (A = P from LDS, B = V^T layout)
    bf16x8 p0 = *(const bf16x8*)(Pw + li * 72 + quad * 8);
    bf16x8 p1 = *(const bf16x8*)(Pw + li * 72 + 32 + quad * 8);
#pragma unroll
    for (int dc = 0; dc < 4; ++dc) {
      bf16x8 bv0 = *(const bf16x8*)(Vsh + (dc * 16 + li) * 72 + quad * 8);
      bf16x8 bv1 = *(const bf16x8*)(Vsh + (dc * 16 + li) * 72 + 32 + quad * 8);
      accO[dc] = __builtin_amdgcn_mfma_f32_16x16x32_bf16(p0, bv0, accO[dc], 0, 0, 0);
      accO[dc] = __builtin_amdgcn_mfma_f32_16x16x32_bf16(p1, bv1, accO[dc], 0, 0, 0);
    }
  }
  // epilogue: O rows quad*4+r need l of those queries
  float lv0 = 1.f / __shfl(l_i, quad * 4 + 0);
  float lv1 = 1.f / __shfl(l_i, quad * 4 + 1);
  float lv2 = 1.f / __shfl(l_i, quad * 4 + 2);
  float lv3 = 1.f / __shfl(l_i, quad * 4 + 3);
#pragma unroll
  for (int dc = 0; dc < 4; ++dc) {
    size_t r0 = tok0 + qt * 64 + wid * 16 + quad * 4;
    size_t col = h * 64 + dc * 16 + li;
    obuf[(r0 + 0) * 512 + col] = f2bf(accO[dc][0] * lv0);
    obuf[(r0 + 1) * 512 + col] = f2bf(accO[dc][1] * lv1);
    obuf[(r0 + 2) * 512 + col] = f2bf(accO[dc][2] * lv2);
    obuf[(r0 + 3) * 512 + col] = f2bf(accO[dc][3] * lv3);
  }
}

extern "C" void kernel_launch(void* const* d_in, const int* in_sizes, int n_in,
                              void* d_out, int out_size, void* d_ws, size_t ws_size,
                              hipStream_t stream) {
  const float* q  = (const float*)d_in[0];
  const float* k  = (const float*)d_in[1];
  const float* v  = (const float*)d_in[2];
  const int* mask = (const int*)d_in[3];
  const float* Wq = (const float*)d_in[4];
  const float* Wk = (const float*)d_in[5];
  const float* Wv = (const float*)d_in[6];
  const float* Wo = (const float*)d_in[7];
  float* out = (float*)d_out;

  char* ws = (char*)d_ws;
  const size_t SA = (size_t)8192 * 512 * 2;  // 8 MB
  unsigned short* qhb = (unsigned short*)(ws);
  unsigned short* khb = (unsigned short*)(ws + SA);
  unsigned short* vhb = (unsigned short*)(ws + 2 * SA);
  unsigned short* vtb = (unsigned short*)(ws + 3 * SA);
  unsigned short* ob  = (unsigned short*)(ws + 4 * SA);
  unsigned short* wqT = (unsigned short*)(ws + 5 * SA);
  unsigned short* wkT = wqT + 512 * 512;
  unsigned short* wvT = wkT + 512 * 512;
  unsigned short* woT = wvT + 512 * 512;

  dim3 wg(8, 8);
  wtrans<<<wg, 256, 0, stream>>>(Wq, wqT);
  wtrans<<<wg, 256, 0, stream>>>(Wk, wkT);
  wtrans<<<wg, 256, 0, stream>>>(Wv, wvT);
  wtrans<<<wg, 256, 0, stream>>>(Wo, woT);
  const float qscale = 0.125f * 1.44269504f;  // 1/sqrt(64) * log2(e)
  dim3 gg(128, 8);
  gemm_tn<1, 0><<<gg, 256, 0, stream>>>(q, nullptr, wqT, qhb, nullptr, qscale, 8192, 512, 512);
  gemm_tn<1, 0><<<gg, 256, 0, stream>>>(k, nullptr, wkT, khb, nullptr, 1.0f, 8192, 512, 512);
  gemm_tn<1, 0><<<gg, 256, 0, stream>>>(v, nullptr, wvT, vhb, nullptr, 1.0f, 8192, 512, 512);
  dim3 vg(64, 16);
  vtrans<<<vg, 256, 0, stream>>>(vhb, vtb);
  dim3 ag(64, 8, 2);
  attn<<<ag, 256, 0, stream>>>(qhb, khb, vtb, mask, ob);
  gemm_tn<0, 1><<<gg, 256, 0, stream>>>(nullptr, ob, woT, nullptr, out, 1.0f, 8192, 512, 512);
}

// Round 3
// 268.416 us; speedup vs baseline: 1.5198x; 1.3008x over previous
//
#include <hip/hip_runtime.h>

typedef short bf16x8 __attribute__((ext_vector_type(8)));
typedef float f32x4 __attribute__((ext_vector_type(4)));
typedef unsigned short u16x8 __attribute__((ext_vector_type(8)));

static __device__ __forceinline__ unsigned short f2bf(float f) {
  unsigned int x = __builtin_bit_cast(unsigned int, f);
  x += 0x7FFFu + ((x >> 16) & 1u);   // RNE
  return (unsigned short)(x >> 16);
}
// pack two floats' bf16 (round-half-up) into one u32 (lo=a, hi=b)
static __device__ __forceinline__ unsigned int pk2bf(float a, float b) {
  unsigned int ia = __builtin_bit_cast(unsigned int, a) + 0x8000u;
  unsigned int ib = __builtin_bit_cast(unsigned int, b) + 0x8000u;
  return __builtin_amdgcn_perm(ib, ia, 0x07060302u);
}
// async 16B global -> LDS (dest must be wave-uniform base + lane*16; we pass base+lane*16)
static __device__ __forceinline__ void gl2lds16(const unsigned short* g, unsigned short* l) {
  __builtin_amdgcn_global_load_lds(
      (const __attribute__((address_space(1))) unsigned int*)g,
      (__attribute__((address_space(3))) unsigned int*)l, 16, 0, 0);
}

// ---------------- fused q/k/v fp32 -> bf16 (8 elems/thread) ----------------
__global__ __launch_bounds__(256) void cvt3(const float* __restrict__ q, const float* __restrict__ k,
                                            const float* __restrict__ v,
                                            unsigned short* __restrict__ qo, unsigned short* __restrict__ ko,
                                            unsigned short* __restrict__ vo) {
  const float* src = (blockIdx.y == 0) ? q : (blockIdx.y == 1) ? k : v;
  unsigned short* dst = (blockIdx.y == 0) ? qo : (blockIdx.y == 1) ? ko : vo;
  int i = (blockIdx.x * 256 + threadIdx.x) * 8;
  float4 a = *(const float4*)(src + i);
  float4 b = *(const float4*)(src + i + 4);
  uint4 pk;
  pk.x = pk2bf(a.x, a.y); pk.y = pk2bf(a.z, a.w);
  pk.z = pk2bf(b.x, b.y); pk.w = pk2bf(b.z, b.w);
  *(uint4*)(dst + i) = pk;
}

// ---------------- W [512k][512n] f32 -> WT [512n][512k] bf16 ----------------
__global__ __launch_bounds__(256) void wtrans(const float* __restrict__ W,
                                              unsigned short* __restrict__ WT) {
  __shared__ __align__(16) float T[64 * 68];
  const int k0 = blockIdx.x * 64, n0 = blockIdx.y * 64;
  const int tid = threadIdx.x;
#pragma unroll
  for (int i = 0; i < 4; ++i) {
    int chunk = i * 256 + tid;
    int row = chunk >> 4, fc = chunk & 15;
    *(float4*)(T + row * 68 + fc * 4) =
        *(const float4*)(W + (size_t)(k0 + row) * 512 + n0 + fc * 4);
  }
  __syncthreads();
#pragma unroll
  for (int i = 0; i < 2; ++i) {
    int chunk = i * 256 + tid;
    int nr = chunk >> 3, kc = chunk & 7;
    u16x8 v;
#pragma unroll
    for (int j = 0; j < 8; ++j) v[j] = f2bf(T[(kc * 8 + j) * 68 + nr]);
    *(u16x8*)(WT + (size_t)(n0 + nr) * 512 + k0 + kc * 8) = v;
  }
}

// ---- TN GEMM: C[M,N] = A[M,K] * Bt[N,K]^T. 128x64 tile, BK=64, async dbuf pipeline. ----
template <int OUT_F32>
__global__ __launch_bounds__(256) void gemm_tn(const unsigned short* __restrict__ A,
                                               const unsigned short* __restrict__ Bt,
                                               unsigned short* __restrict__ Cb,
                                               float* __restrict__ Cf,
                                               float scale, int M, int N, int K) {
  __shared__ __align__(16) unsigned short Abuf[2][128 * 64];  // XOR-swizzled 16B chunks
  __shared__ __align__(16) unsigned short Bbuf[2][64 * 64];
  const int tid = threadIdx.x;
  const int wid = tid >> 6, lane = tid & 63, quad = lane >> 4, li = lane & 15;
  const int bm = blockIdx.x * 128, bn = blockIdx.y * 64;
  const int wm = wid * 32;
  // staging plan: per lane 6 chunks; i=0..3 -> A (1024 chunks), i=4..5 -> B (512 chunks)
  const unsigned short* ga[4]; int oa[4];
  const unsigned short* gb[2]; int ob[2];
#pragma unroll
  for (int i = 0; i < 4; ++i) {
    int lam = i * 256 + wid * 64 + lane;
    int r = lam >> 3, c = (lam & 7) ^ (r & 7);
    ga[i] = A + (size_t)(bm + r) * K + c * 8;
    oa[i] = lam * 8;
  }
#pragma unroll
  for (int i = 0; i < 2; ++i) {
    int lam = i * 256 + wid * 64 + lane;
    int r = lam >> 3, c = (lam & 7) ^ (r & 7);
    gb[i] = Bt + (size_t)(bn + r) * K + c * 8;
    ob[i] = lam * 8;
  }
  // prologue: issue step 0 into buf 0
#pragma unroll
  for (int i = 0; i < 4; ++i) { gl2lds16(ga[i], &Abuf[0][oa[i]]); ga[i] += 64; }
#pragma unroll
  for (int i = 0; i < 2; ++i) { gl2lds16(gb[i], &Bbuf[0][ob[i]]); gb[i] += 64; }

  f32x4 acc[2][4] = {};
  const int nstep = K >> 6;
  const int sw = li & 7;
  for (int s = 0; s < nstep; ++s) {
    __syncthreads();                       // drains step-s loads (issued a full step ago)
    if (s + 1 < nstep) {
      int p = (s + 1) & 1;
#pragma unroll
      for (int i = 0; i < 4; ++i) { gl2lds16(ga[i], &Abuf[p][oa[i]]); ga[i] += 64; }
#pragma unroll
      for (int i = 0; i < 2; ++i) { gl2lds16(gb[i], &Bbuf[p][ob[i]]); gb[i] += 64; }
    }
    const unsigned short* As = &Abuf[s & 1][0];
    const unsigned short* Bs = &Bbuf[s & 1][0];
#pragma unroll
    for (int kk = 0; kk < 2; ++kk) {
      bf16x8 af[2], bfr[4];
#pragma unroll
      for (int t = 0; t < 2; ++t)
        af[t] = *(const bf16x8*)(As + (wm + t * 16 + li) * 64 + (((kk * 4 + quad) ^ sw) * 8));
#pragma unroll
      for (int t = 0; t < 4; ++t)
        bfr[t] = *(const bf16x8*)(Bs + (t * 16 + li) * 64 + (((kk * 4 + quad) ^ sw) * 8));
#pragma unroll
      for (int mt = 0; mt < 2; ++mt)
#pragma unroll
        for (int nt = 0; nt < 4; ++nt)
          acc[mt][nt] = __builtin_amdgcn_mfma_f32_16x16x32_bf16(af[mt], bfr[nt], acc[mt][nt], 0, 0, 0);
    }
  }
#pragma unroll
  for (int mt = 0; mt < 2; ++mt)
#pragma unroll
    for (int nt = 0; nt < 4; ++nt) {
      int r0 = bm + wm + mt * 16 + quad * 4;
      int c  = bn + nt * 16 + li;
#pragma unroll
      for (int r = 0; r < 4; ++r) {
        float v = acc[mt][nt][r] * scale;
        if (OUT_F32) Cf[(size_t)(r0 + r) * N + c] = v;
        else         Cb[(size_t)(r0 + r) * N + c] = f2bf(v);
      }
    }
}

// ---------------- vh [B*L][512] -> vt [(b*8+h)*64+d][4096]  (per-head V^T) ----------------
__global__ __launch_bounds__(256) void vtrans(const unsigned short* __restrict__ vh,
                                              unsigned short* __restrict__ vt) {
  __shared__ __align__(16) unsigned short T[64 * 72];
  const int kt = blockIdx.x;
  const int bh = blockIdx.y;
  const int b = bh >> 3, h = bh & 7;
  const int tid = threadIdx.x;
#pragma unroll
  for (int i = 0; i < 2; ++i) {
    int chunk = i * 256 + tid;
    int row = chunk >> 3, c8 = chunk & 7;
    *(uint4*)(T + row * 72 + c8 * 8) =
        *(const uint4*)(vh + (size_t)(b * 4096 + kt * 64 + row) * 512 + h * 64 + c8 * 8);
  }
  __syncthreads();
#pragma unroll
  for (int i = 0; i < 2; ++i) {
    int chunk = i * 256 + tid;
    int dr = chunk >> 3, c8 = chunk & 7;
    u16x8 v;
#pragma unroll
    for (int j = 0; j < 8; ++j) v[j] = T[(c8 * 8 + j) * 72 + dr];
    *(u16x8*)(vt + (size_t)(bh * 64 + dr) * 4096 + kt * 64 + c8 * 8) = v;
  }
}

// ---- flash attention, S^T form: block = (qt:128q, h, b); 8 waves x 16q; async dbuf K/V ----
// qh PRE-SCALED by 1/sqrt(64)*log2(e); exp2 domain.
__global__ __launch_bounds__(512) void attn(const unsigned short* __restrict__ qh,
                                            const unsigned short* __restrict__ kh,
                                            const unsigned short* __restrict__ vt,
                                            const int* __restrict__ mask,
                                            unsigned short* __restrict__ obuf) {
  __shared__ __align__(16) unsigned short Kbuf[2][64 * 64];   // [key][dim], swizzled chunks
  __shared__ __align__(16) unsigned short Vbuf[2][64 * 64];   // [dim][key], swizzled chunks
  __shared__ __align__(16) unsigned short Psh[8][16 * 72];    // per-wave P [q][k]
  __shared__ __align__(16) unsigned short MskBits[256];       // validity bitmask, 16 keys/entry
  const int qt = blockIdx.x, h = blockIdx.y, b = blockIdx.z;
  const int tid = threadIdx.x;
  const int wid = tid >> 6, lane = tid & 63, quad = lane >> 4, li = lane & 15;
  const size_t tok0 = (size_t)b * 4096;

  if (tid < 256) {
    const int4* mp = (const int4*)(mask + b * 4096 + tid * 16);
    unsigned int bits = 0;
#pragma unroll
    for (int j = 0; j < 4; ++j) {
      int4 m4 = mp[j];
      bits |= (m4.x ? 1u : 0u) << (j * 4 + 0);
      bits |= (m4.y ? 1u : 0u) << (j * 4 + 1);
      bits |= (m4.z ? 1u : 0u) << (j * 4 + 2);
      bits |= (m4.w ? 1u : 0u) << (j * 4 + 3);
    }
    MskBits[tid] = (unsigned short)bits;
  }

  // Q as B-operand: lane holds Q[qrow][d=quad*8+j]
  const unsigned short* qp = qh + (tok0 + qt * 128 + wid * 16 + li) * 512 + h * 64;
  bf16x8 bq0 = *(const bf16x8*)(qp + quad * 8);
  bf16x8 bq1 = *(const bf16x8*)(qp + 32 + quad * 8);

  // staging: waves 0-3 stage K (512 chunks), waves 4-7 stage V; 2 chunks/lane
  const unsigned short* kbase = kh + tok0 * 512 + h * 64;
  const unsigned short* vbase = vt + (size_t)(b * 8 + h) * 64 * 4096;
  const int wk = wid & 3;
  const int lam0 = wk * 128 + lane, lam1 = lam0 + 64;
  const int r0 = lam0 >> 3, c0 = (lam0 & 7) ^ (r0 & 7);
  const int r1 = lam1 >> 3, c1 = (lam1 & 7) ^ (r1 & 7);
  const unsigned short *g0, *g1;
  size_t kstride;
  unsigned short *lb0, *lb1;
  if (wid < 4) {
    g0 = kbase + (size_t)r0 * 512 + c0 * 8;
    g1 = kbase + (size_t)r1 * 512 + c1 * 8;
    kstride = 64 * 512;
    lb0 = &Kbuf[0][0]; lb1 = &Kbuf[1][0];
  } else {
    g0 = vbase + (size_t)r0 * 4096 + c0 * 8;
    g1 = vbase + (size_t)r1 * 4096 + c1 * 8;
    kstride = 64;
    lb0 = &Vbuf[0][0]; lb1 = &Vbuf[1][0];
  }
  const int o0 = lam0 * 8, o1 = lam1 * 8;

  // prologue: issue tile 0 into buf 0
  gl2lds16(g0, lb0 + o0);
  gl2lds16(g1, lb0 + o1);
  g0 += kstride; g1 += kstride;

  float m_i = -1e30f, l_i = 0.f;
  f32x4 accO[4] = {};
  unsigned short* Pw = &Psh[wid][0];
  const int sw = li & 7;

  for (int t = 0; t < 64; ++t) {
    __syncthreads();                       // drains tile-t loads (issued a full tile ago)
    if (t < 63) {
      unsigned short* lb = ((t + 1) & 1) ? lb1 : lb0;
      gl2lds16(g0, lb + o0);
      gl2lds16(g1, lb + o1);
      g0 += kstride; g1 += kstride;
    }
    const unsigned short* Ks = &Kbuf[t & 1][0];
    const unsigned short* Vs = &Vbuf[t & 1][0];

    // S^T = K Q^T: lane holds query q=li, keys kb*16 + quad*4 + r
    f32x4 s[4];
#pragma unroll
    for (int kb = 0; kb < 4; ++kb) {
      const unsigned short* kr = Ks + (kb * 16 + li) * 64;
      bf16x8 ak0 = *(const bf16x8*)(kr + ((quad ^ sw) * 8));
      bf16x8 ak1 = *(const bf16x8*)(kr + (((4 + quad) ^ sw) * 8));
      f32x4 z = {};
      z = __builtin_amdgcn_mfma_f32_16x16x32_bf16(ak0, bq0, z, 0, 0, 0);
      z = __builtin_amdgcn_mfma_f32_16x16x32_bf16(ak1, bq1, z, 0, 0, 0);
      s[kb] = z;
    }
    unsigned long long mbits = *(const unsigned long long*)(MskBits + t * 4);
    if (mbits != ~0ull) {
#pragma unroll
      for (int kb = 0; kb < 4; ++kb)
#pragma unroll
        for (int r = 0; r < 4; ++r) {
          int key = kb * 16 + quad * 4 + r;
          if (!((mbits >> key) & 1ull)) s[kb][r] = -1e30f;
        }
    }
    // online softmax over keys (per-lane query)
    float mx = s[0][0];
#pragma unroll
    for (int kb = 0; kb < 4; ++kb)
#pragma unroll
      for (int r = 0; r < 4; ++r) mx = fmaxf(mx, s[kb][r]);
    mx = fmaxf(mx, __shfl_xor(mx, 16));
    mx = fmaxf(mx, __shfl_xor(mx, 32));
    float mn = fmaxf(m_i, mx);
    float alpha = __builtin_amdgcn_exp2f(m_i - mn);
    m_i = mn;
    float rs = 0.f;
#pragma unroll
    for (int kb = 0; kb < 4; ++kb)
#pragma unroll
      for (int r = 0; r < 4; ++r) {
        float p = __builtin_amdgcn_exp2f(s[kb][r] - mn);
        s[kb][r] = p;
        rs += p;
      }
    rs += __shfl_xor(rs, 16);
    rs += __shfl_xor(rs, 32);
    l_i = l_i * alpha + rs;
    // P[q=li][k] bf16 -> per-wave LDS
#pragma unroll
    for (int kb = 0; kb < 4; ++kb) {
      uint2 pk;
      pk.x = pk2bf(s[kb][0], s[kb][1]);
      pk.y = pk2bf(s[kb][2], s[kb][3]);
      *(uint2*)(Pw + li * 72 + kb * 16 + quad * 4) = pk;
    }
    // rescale O rows (rows are queries quad*4+r)
    float av0 = __shfl(alpha, quad * 4 + 0);
    float av1 = __shfl(alpha, quad * 4 + 1);
    float av2 = __shfl(alpha, quad * 4 + 2);
    float av3 = __shfl(alpha, quad * 4 + 3);
#pragma unroll
    for (int dc = 0; dc < 4; ++dc) {
      accO[dc][0] *= av0; accO[dc][1] *= av1;
      accO[dc][2] *= av2; accO[dc][3] *= av3;
    }
    // O += P V
    bf16x8 p0 = *(const bf16x8*)(Pw + li * 72 + quad * 8);
    bf16x8 p1 = *(const bf16x8*)(Pw + li * 72 + 32 + quad * 8);
#pragma unroll
    for (int dc = 0; dc < 4; ++dc) {
      const unsigned short* vr = Vs + (dc * 16 + li) * 64;
      bf16x8 bv0 = *(const bf16x8*)(vr + ((quad ^ sw) * 8));
      bf16x8 bv1 = *(const bf16x8*)(vr + (((4 + quad) ^ sw) * 8));
      accO[dc] = __builtin_amdgcn_mfma_f32_16x16x32_bf16(p0, bv0, accO[dc], 0, 0, 0);
      accO[dc] = __builtin_amdgcn_mfma_f32_16x16x32_bf16(p1, bv1, accO[dc], 0, 0, 0);
    }
  }
  float lv0 = 1.f / __shfl(l_i, quad * 4 + 0);
  float lv1 = 1.f / __shfl(l_i, quad * 4 + 1);
  float lv2 = 1.f / __shfl(l_i, quad * 4 + 2);
  float lv3 = 1.f / __shfl(l_i, quad * 4 + 3);
#pragma unroll
  for (int dc = 0; dc < 4; ++dc) {
    size_t r0q = tok0 + qt * 128 + wid * 16 + quad * 4;
    size_t col = h * 64 + dc * 16 + li;
    obuf[(r0q + 0) * 512 + col] = f2bf(accO[dc][0] * lv0);
    obuf[(r0q + 1) * 512 + col] = f2bf(accO[dc][1] * lv1);
    obuf[(r0q + 2) * 512 + col] = f2bf(accO[dc][2] * lv2);
    obuf[(r0q + 3) * 512 + col] = f2bf(accO[dc][3] * lv3);
  }
}

extern "C" void kernel_launch(void* const* d_in, const int* in_sizes, int n_in,
                              void* d_out, int out_size, void* d_ws, size_t ws_size,
                              hipStream_t stream) {
  const float* q  = (const float*)d_in[0];
  const float* k  = (const float*)d_in[1];
  const float* v  = (const float*)d_in[2];
  const int* mask = (const int*)d_in[3];
  const float* Wq = (const float*)d_in[4];
  const float* Wk = (const float*)d_in[5];
  const float* Wv = (const float*)d_in[6];
  const float* Wo = (const float*)d_in[7];
  float* out = (float*)d_out;

  char* ws = (char*)d_ws;
  const size_t SA = (size_t)8192 * 512 * 2;  // 8 MB
  unsigned short* qbf = (unsigned short*)(ws);
  unsigned short* kbf = (unsigned short*)(ws + SA);
  unsigned short* vbf = (unsigned short*)(ws + 2 * SA);
  unsigned short* qhb = (unsigned short*)(ws + 3 * SA);
  unsigned short* khb = (unsigned short*)(ws + 4 * SA);
  unsigned short* vhb = (unsigned short*)(ws + 5 * SA);
  unsigned short* wqT = (unsigned short*)(ws + 6 * SA);
  unsigned short* wkT = wqT + 512 * 512;
  unsigned short* wvT = wkT + 512 * 512;
  unsigned short* woT = wvT + 512 * 512;
  unsigned short* vtb = qbf;  // reuse: qbf dead after Q GEMM
  unsigned short* ob  = kbf;  // reuse: kbf dead after K GEMM

  dim3 cg(2048, 3);
  cvt3<<<cg, 256, 0, stream>>>(q, k, v, qbf, kbf, vbf);
  dim3 wg(8, 8);
  wtrans<<<wg, 256, 0, stream>>>(Wq, wqT);
  wtrans<<<wg, 256, 0, stream>>>(Wk, wkT);
  wtrans<<<wg, 256, 0, stream>>>(Wv, wvT);
  wtrans<<<wg, 256, 0, stream>>>(Wo, woT);
  const float qscale = 0.125f * 1.44269504f;  // 1/sqrt(64) * log2(e)
  dim3 gg(64, 8);
  gemm_tn<0><<<gg, 256, 0, stream>>>(qbf, wqT, qhb, nullptr, qscale, 8192, 512, 512);
  gemm_tn<0><<<gg, 256, 0, stream>>>(kbf, wkT, khb, nullptr, 1.0f, 8192, 512, 512);
  gemm_tn<0><<<gg, 256, 0, stream>>>(vbf, wvT, vhb, nullptr, 1.0f, 8192, 512, 512);
  dim3 vg(64, 16);
  vtrans<<<vg, 256, 0, stream>>>(vhb, vtb);
  dim3 ag(32, 8, 2);
  attn<<<ag, 512, 0, stream>>>(qhb, khb, vtb, mask, ob);
  gemm_tn<1><<<gg, 256, 0, stream>>>(ob, woT, nullptr, out, 1.0f, 8192, 512, 512);
}

// Round 4
// 226.865 us; speedup vs baseline: 1.7982x; 1.1832x over previous
//
#include <hip/hip_runtime.h>

typedef short bf16x8 __attribute__((ext_vector_type(8)));
typedef float f32x4 __attribute__((ext_vector_type(4)));
typedef unsigned short u16x8 __attribute__((ext_vector_type(8)));

static __device__ __forceinline__ unsigned short f2bf(float f) {
  unsigned int x = __builtin_bit_cast(unsigned int, f);
  x += 0x7FFFu + ((x >> 16) & 1u);   // RNE
  return (unsigned short)(x >> 16);
}
// pack two floats' bf16 (round-half-up) into one u32 (lo=a, hi=b)
static __device__ __forceinline__ unsigned int pk2bf(float a, float b) {
  unsigned int ia = __builtin_bit_cast(unsigned int, a) + 0x8000u;
  unsigned int ib = __builtin_bit_cast(unsigned int, b) + 0x8000u;
  return __builtin_amdgcn_perm(ib, ia, 0x07060302u);
}
// async 16B global -> LDS
static __device__ __forceinline__ void gl2lds16(const unsigned short* g, unsigned short* l) {
  __builtin_amdgcn_global_load_lds(
      (const __attribute__((address_space(1))) unsigned int*)g,
      (__attribute__((address_space(3))) unsigned int*)l, 16, 0, 0);
}

// ---------------- fused q/k/v fp32 -> bf16 (8 elems/thread) ----------------
__global__ __launch_bounds__(256) void cvt3(const float* __restrict__ q, const float* __restrict__ k,
                                            const float* __restrict__ v,
                                            unsigned short* __restrict__ qo, unsigned short* __restrict__ ko,
                                            unsigned short* __restrict__ vo) {
  const float* src = (blockIdx.y == 0) ? q : (blockIdx.y == 1) ? k : v;
  unsigned short* dst = (blockIdx.y == 0) ? qo : (blockIdx.y == 1) ? ko : vo;
  int i = (blockIdx.x * 256 + threadIdx.x) * 8;
  float4 a = *(const float4*)(src + i);
  float4 b = *(const float4*)(src + i + 4);
  uint4 pk;
  pk.x = pk2bf(a.x, a.y); pk.y = pk2bf(a.z, a.w);
  pk.z = pk2bf(b.x, b.y); pk.w = pk2bf(b.z, b.w);
  *(uint4*)(dst + i) = pk;
}

// ------- 4x W [512k][512n] f32 -> WT [4][512n][512k] bf16 (z selects matrix) -------
__global__ __launch_bounds__(256) void wtrans4(const float* __restrict__ Wq, const float* __restrict__ Wk,
                                               const float* __restrict__ Wv, const float* __restrict__ Wo,
                                               unsigned short* __restrict__ WT) {
  __shared__ __align__(16) float T[64 * 68];
  const int z = blockIdx.z;
  const float* W = (z == 0) ? Wq : (z == 1) ? Wk : (z == 2) ? Wv : Wo;
  unsigned short* out = WT + (size_t)z * 512 * 512;
  const int k0 = blockIdx.x * 64, n0 = blockIdx.y * 64;
  const int tid = threadIdx.x;
#pragma unroll
  for (int i = 0; i < 4; ++i) {
    int chunk = i * 256 + tid;
    int row = chunk >> 4, fc = chunk & 15;
    *(float4*)(T + row * 68 + fc * 4) =
        *(const float4*)(W + (size_t)(k0 + row) * 512 + n0 + fc * 4);
  }
  __syncthreads();
#pragma unroll
  for (int i = 0; i < 2; ++i) {
    int chunk = i * 256 + tid;
    int nr = chunk >> 3, kc = chunk & 7;
    u16x8 v;
#pragma unroll
    for (int j = 0; j < 8; ++j) v[j] = f2bf(T[(kc * 8 + j) * 68 + nr]);
    *(u16x8*)(out + (size_t)(n0 + nr) * 512 + k0 + kc * 8) = v;
  }
}

// ---- fused QKV GEMM: C[8192][1536] = [q|k|v] proj. 128x64 tile, BK=64, async dbuf. ----
// Bt = concatenated [WqT;WkT;WvT] rows [1536][512]. A selected by N-section.
__global__ __launch_bounds__(256) void gemm_qkv(const unsigned short* __restrict__ Aq,
                                                const unsigned short* __restrict__ Ak,
                                                const unsigned short* __restrict__ Av,
                                                const unsigned short* __restrict__ Bt,
                                                unsigned short* __restrict__ C,
                                                float qscale) {
  __shared__ __align__(16) unsigned short Abuf[2][128 * 64];
  __shared__ __align__(16) unsigned short Bbuf[2][64 * 64];
  const int K = 512, LDC = 1536;
  const unsigned short* A = (blockIdx.y < 8) ? Aq : (blockIdx.y < 16) ? Ak : Av;
  const float scale = (blockIdx.y < 8) ? qscale : 1.0f;
  const int tid = threadIdx.x;
  const int wid = tid >> 6, lane = tid & 63, quad = lane >> 4, li = lane & 15;
  const int bm = blockIdx.x * 128, bn = blockIdx.y * 64;
  const int wm = wid * 32;
  const unsigned short* ga[4]; int oa[4];
  const unsigned short* gb[2]; int ob[2];
#pragma unroll
  for (int i = 0; i < 4; ++i) {
    int lam = i * 256 + wid * 64 + lane;
    int r = lam >> 3, c = (lam & 7) ^ (r & 7);
    ga[i] = A + (size_t)(bm + r) * K + c * 8;
    oa[i] = lam * 8;
  }
#pragma unroll
  for (int i = 0; i < 2; ++i) {
    int lam = i * 256 + wid * 64 + lane;
    int r = lam >> 3, c = (lam & 7) ^ (r & 7);
    gb[i] = Bt + (size_t)(bn + r) * K + c * 8;
    ob[i] = lam * 8;
  }
#pragma unroll
  for (int i = 0; i < 4; ++i) { gl2lds16(ga[i], &Abuf[0][oa[i]]); ga[i] += 64; }
#pragma unroll
  for (int i = 0; i < 2; ++i) { gl2lds16(gb[i], &Bbuf[0][ob[i]]); gb[i] += 64; }

  f32x4 acc[2][4] = {};
  const int sw = li & 7;
  for (int s = 0; s < 8; ++s) {
    __syncthreads();
    if (s + 1 < 8) {
      int p = (s + 1) & 1;
#pragma unroll
      for (int i = 0; i < 4; ++i) { gl2lds16(ga[i], &Abuf[p][oa[i]]); ga[i] += 64; }
#pragma unroll
      for (int i = 0; i < 2; ++i) { gl2lds16(gb[i], &Bbuf[p][ob[i]]); gb[i] += 64; }
    }
    const unsigned short* As = &Abuf[s & 1][0];
    const unsigned short* Bs = &Bbuf[s & 1][0];
#pragma unroll
    for (int kk = 0; kk < 2; ++kk) {
      bf16x8 af[2], bfr[4];
#pragma unroll
      for (int t = 0; t < 2; ++t)
        af[t] = *(const bf16x8*)(As + (wm + t * 16 + li) * 64 + (((kk * 4 + quad) ^ sw) * 8));
#pragma unroll
      for (int t = 0; t < 4; ++t)
        bfr[t] = *(const bf16x8*)(Bs + (t * 16 + li) * 64 + (((kk * 4 + quad) ^ sw) * 8));
#pragma unroll
      for (int mt = 0; mt < 2; ++mt)
#pragma unroll
        for (int nt = 0; nt < 4; ++nt)
          acc[mt][nt] = __builtin_amdgcn_mfma_f32_16x16x32_bf16(af[mt], bfr[nt], acc[mt][nt], 0, 0, 0);
    }
  }
#pragma unroll
  for (int mt = 0; mt < 2; ++mt)
#pragma unroll
    for (int nt = 0; nt < 4; ++nt) {
      int r0 = bm + wm + mt * 16 + quad * 4;
      int c  = bn + nt * 16 + li;
#pragma unroll
      for (int r = 0; r < 4; ++r)
        C[(size_t)(r0 + r) * LDC + c] = f2bf(acc[mt][nt][r] * scale);
    }
}

// ---- O-proj GEMM: out[8192][512] f32 = ob[8192][512] * WoT^T. Same structure. ----
__global__ __launch_bounds__(256) void gemm_o(const unsigned short* __restrict__ A,
                                              const unsigned short* __restrict__ Bt,
                                              float* __restrict__ Cf) {
  __shared__ __align__(16) unsigned short Abuf[2][128 * 64];
  __shared__ __align__(16) unsigned short Bbuf[2][64 * 64];
  const int K = 512, LDC = 512;
  const int tid = threadIdx.x;
  const int wid = tid >> 6, lane = tid & 63, quad = lane >> 4, li = lane & 15;
  const int bm = blockIdx.x * 128, bn = blockIdx.y * 64;
  const int wm = wid * 32;
  const unsigned short* ga[4]; int oa[4];
  const unsigned short* gb[2]; int ob[2];
#pragma unroll
  for (int i = 0; i < 4; ++i) {
    int lam = i * 256 + wid * 64 + lane;
    int r = lam >> 3, c = (lam & 7) ^ (r & 7);
    ga[i] = A + (size_t)(bm + r) * K + c * 8;
    oa[i] = lam * 8;
  }
#pragma unroll
  for (int i = 0; i < 2; ++i) {
    int lam = i * 256 + wid * 64 + lane;
    int r = lam >> 3, c = (lam & 7) ^ (r & 7);
    gb[i] = Bt + (size_t)(bn + r) * K + c * 8;
    ob[i] = lam * 8;
  }
#pragma unroll
  for (int i = 0; i < 4; ++i) { gl2lds16(ga[i], &Abuf[0][oa[i]]); ga[i] += 64; }
#pragma unroll
  for (int i = 0; i < 2; ++i) { gl2lds16(gb[i], &Bbuf[0][ob[i]]); gb[i] += 64; }

  f32x4 acc[2][4] = {};
  const int sw = li & 7;
  for (int s = 0; s < 8; ++s) {
    __syncthreads();
    if (s + 1 < 8) {
      int p = (s + 1) & 1;
#pragma unroll
      for (int i = 0; i < 4; ++i) { gl2lds16(ga[i], &Abuf[p][oa[i]]); ga[i] += 64; }
#pragma unroll
      for (int i = 0; i < 2; ++i) { gl2lds16(gb[i], &Bbuf[p][ob[i]]); gb[i] += 64; }
    }
    const unsigned short* As = &Abuf[s & 1][0];
    const unsigned short* Bs = &Bbuf[s & 1][0];
#pragma unroll
    for (int kk = 0; kk < 2; ++kk) {
      bf16x8 af[2], bfr[4];
#pragma unroll
      for (int t = 0; t < 2; ++t)
        af[t] = *(const bf16x8*)(As + (wm + t * 16 + li) * 64 + (((kk * 4 + quad) ^ sw) * 8));
#pragma unroll
      for (int t = 0; t < 4; ++t)
        bfr[t] = *(const bf16x8*)(Bs + (t * 16 + li) * 64 + (((kk * 4 + quad) ^ sw) * 8));
#pragma unroll
      for (int mt = 0; mt < 2; ++mt)
#pragma unroll
        for (int nt = 0; nt < 4; ++nt)
          acc[mt][nt] = __builtin_amdgcn_mfma_f32_16x16x32_bf16(af[mt], bfr[nt], acc[mt][nt], 0, 0, 0);
    }
  }
#pragma unroll
  for (int mt = 0; mt < 2; ++mt)
#pragma unroll
    for (int nt = 0; nt < 4; ++nt) {
      int r0 = bm + wm + mt * 16 + quad * 4;
      int c  = bn + nt * 16 + li;
#pragma unroll
      for (int r = 0; r < 4; ++r)
        Cf[(size_t)(r0 + r) * LDC + c] = acc[mt][nt][r];
    }
}

// ---- qkvh V-section [B*L][1536]+1024 -> vt [(b*8+h)*64+d][4096] (per-head V^T) ----
__global__ __launch_bounds__(256) void vtrans(const unsigned short* __restrict__ qkv,
                                              unsigned short* __restrict__ vt) {
  __shared__ __align__(16) unsigned short T[64 * 72];
  const int kt = blockIdx.x;
  const int bh = blockIdx.y;
  const int b = bh >> 3, h = bh & 7;
  const int tid = threadIdx.x;
#pragma unroll
  for (int i = 0; i < 2; ++i) {
    int chunk = i * 256 + tid;
    int row = chunk >> 3, c8 = chunk & 7;
    *(uint4*)(T + row * 72 + c8 * 8) =
        *(const uint4*)(qkv + (size_t)(b * 4096 + kt * 64 + row) * 1536 + 1024 + h * 64 + c8 * 8);
  }
  __syncthreads();
#pragma unroll
  for (int i = 0; i < 2; ++i) {
    int chunk = i * 256 + tid;
    int dr = chunk >> 3, c8 = chunk & 7;
    u16x8 v;
#pragma unroll
    for (int j = 0; j < 8; ++j) v[j] = T[(c8 * 8 + j) * 72 + dr];
    *(u16x8*)(vt + (size_t)(bh * 64 + dr) * 4096 + kt * 64 + c8 * 8) = v;
  }
}

// ---- flash attention, S^T form, NO-MAX softmax (scores bounded; exact math). ----
// block = (qt:128q, h, b); 8 waves x 16q; async dbuf K/V. qh pre-scaled by 1/8*log2(e).
__global__ __launch_bounds__(512) void attn(const unsigned short* __restrict__ qkv,
                                            const unsigned short* __restrict__ vt,
                                            const int* __restrict__ mask,
                                            unsigned short* __restrict__ obuf) {
  __shared__ __align__(16) unsigned short Kbuf[2][64 * 64];   // [key][dim], swizzled
  __shared__ __align__(16) unsigned short Vbuf[2][64 * 64];   // [dim][key], swizzled
  __shared__ __align__(16) unsigned short Psh[8][16 * 72];    // per-wave P [q][k]
  __shared__ __align__(16) unsigned short MskBits[256];
  const int qt = blockIdx.x, h = blockIdx.y, b = blockIdx.z;
  const int tid = threadIdx.x;
  const int wid = tid >> 6, lane = tid & 63, quad = lane >> 4, li = lane & 15;
  const size_t tok0 = (size_t)b * 4096;

  if (tid < 256) {
    const int4* mp = (const int4*)(mask + b * 4096 + tid * 16);
    unsigned int bits = 0;
#pragma unroll
    for (int j = 0; j < 4; ++j) {
      int4 m4 = mp[j];
      bits |= (m4.x ? 1u : 0u) << (j * 4 + 0);
      bits |= (m4.y ? 1u : 0u) << (j * 4 + 1);
      bits |= (m4.z ? 1u : 0u) << (j * 4 + 2);
      bits |= (m4.w ? 1u : 0u) << (j * 4 + 3);
    }
    MskBits[tid] = (unsigned short)bits;
  }

  // Q as B-operand (cols 0-511 of qkv)
  const unsigned short* qp = qkv + (tok0 + qt * 128 + wid * 16 + li) * 1536 + h * 64;
  bf16x8 bq0 = *(const bf16x8*)(qp + quad * 8);
  bf16x8 bq1 = *(const bf16x8*)(qp + 32 + quad * 8);

  // staging: waves 0-3 stage K (cols 512-1023), waves 4-7 stage V^T
  const unsigned short* kbase = qkv + tok0 * 1536 + 512 + h * 64;
  const unsigned short* vbase = vt + (size_t)(b * 8 + h) * 64 * 4096;
  const int wk = wid & 3;
  const int lam0 = wk * 128 + lane, lam1 = lam0 + 64;
  const int r0 = lam0 >> 3, c0 = (lam0 & 7) ^ (r0 & 7);
  const int r1 = lam1 >> 3, c1 = (lam1 & 7) ^ (r1 & 7);
  const unsigned short *g0, *g1;
  size_t kstride;
  unsigned short *lb0, *lb1;
  if (wid < 4) {
    g0 = kbase + (size_t)r0 * 1536 + c0 * 8;
    g1 = kbase + (size_t)r1 * 1536 + c1 * 8;
    kstride = (size_t)64 * 1536;
    lb0 = &Kbuf[0][0]; lb1 = &Kbuf[1][0];
  } else {
    g0 = vbase + (size_t)r0 * 4096 + c0 * 8;
    g1 = vbase + (size_t)r1 * 4096 + c1 * 8;
    kstride = 64;
    lb0 = &Vbuf[0][0]; lb1 = &Vbuf[1][0];
  }
  const int o0 = lam0 * 8, o1 = lam1 * 8;

  gl2lds16(g0, lb0 + o0);
  gl2lds16(g1, lb0 + o1);
  g0 += kstride; g1 += kstride;

  f32x4 lacc = {};
  f32x4 accO[4] = {};
  unsigned short* Pw = &Psh[wid][0];
  const int sw = li & 7;

  for (int t = 0; t < 64; ++t) {
    __syncthreads();
    if (t < 63) {
      unsigned short* lb = ((t + 1) & 1) ? lb1 : lb0;
      gl2lds16(g0, lb + o0);
      gl2lds16(g1, lb + o1);
      g0 += kstride; g1 += kstride;
    }
    const unsigned short* Ks = &Kbuf[t & 1][0];
    const unsigned short* Vs = &Vbuf[t & 1][0];

    // S^T = K Q^T: lane = query li; keys kb*16 + quad*4 + r
    f32x4 s[4];
#pragma unroll
    for (int kb = 0; kb < 4; ++kb) {
      const unsigned short* kr = Ks + (kb * 16 + li) * 64;
      bf16x8 ak0 = *(const bf16x8*)(kr + ((quad ^ sw) * 8));
      bf16x8 ak1 = *(const bf16x8*)(kr + (((4 + quad) ^ sw) * 8));
      f32x4 z = {};
      z = __builtin_amdgcn_mfma_f32_16x16x32_bf16(ak0, bq0, z, 0, 0, 0);
      z = __builtin_amdgcn_mfma_f32_16x16x32_bf16(ak1, bq1, z, 0, 0, 0);
      s[kb] = z;
    }
    unsigned long long mbits = *(const unsigned long long*)(MskBits + t * 4);
    if (mbits != ~0ull) {
#pragma unroll
      for (int kb = 0; kb < 4; ++kb)
#pragma unroll
        for (int r = 0; r < 4; ++r) {
          int key = kb * 16 + quad * 4 + r;
          if (!((mbits >> key) & 1ull)) s[kb][r] = -1e30f;
        }
    }
    // p = exp2(s); per-lane partial l; pack to bf16 P
#pragma unroll
    for (int kb = 0; kb < 4; ++kb) {
#pragma unroll
      for (int r = 0; r < 4; ++r) s[kb][r] = __builtin_amdgcn_exp2f(s[kb][r]);
      lacc += s[kb];
      uint2 pk;
      pk.x = pk2bf(s[kb][0], s[kb][1]);
      pk.y = pk2bf(s[kb][2], s[kb][3]);
      *(uint2*)(Pw + li * 72 + kb * 16 + quad * 4) = pk;
    }
    // O += P V
    bf16x8 p0 = *(const bf16x8*)(Pw + li * 72 + quad * 8);
    bf16x8 p1 = *(const bf16x8*)(Pw + li * 72 + 32 + quad * 8);
#pragma unroll
    for (int dc = 0; dc < 4; ++dc) {
      const unsigned short* vr = Vs + (dc * 16 + li) * 64;
      bf16x8 bv0 = *(const bf16x8*)(vr + ((quad ^ sw) * 8));
      bf16x8 bv1 = *(const bf16x8*)(vr + (((4 + quad) ^ sw) * 8));
      accO[dc] = __builtin_amdgcn_mfma_f32_16x16x32_bf16(p0, bv0, accO[dc], 0, 0, 0);
      accO[dc] = __builtin_amdgcn_mfma_f32_16x16x32_bf16(p1, bv1, accO[dc], 0, 0, 0);
    }
  }
  // epilogue: full l per query, then normalize
  float lt = lacc[0] + lacc[1] + lacc[2] + lacc[3];
  lt += __shfl_xor(lt, 16);
  lt += __shfl_xor(lt, 32);
  float lv0 = 1.f / __shfl(lt, quad * 4 + 0);
  float lv1 = 1.f / __shfl(lt, quad * 4 + 1);
  float lv2 = 1.f / __shfl(lt, quad * 4 + 2);
  float lv3 = 1.f / __shfl(lt, quad * 4 + 3);
#pragma unroll
  for (int dc = 0; dc < 4; ++dc) {
    size_t r0q = tok0 + qt * 128 + wid * 16 + quad * 4;
    size_t col = h * 64 + dc * 16 + li;
    obuf[(r0q + 0) * 512 + col] = f2bf(accO[dc][0] * lv0);
    obuf[(r0q + 1) * 512 + col] = f2bf(accO[dc][1] * lv1);
    obuf[(r0q + 2) * 512 + col] = f2bf(accO[dc][2] * lv2);
    obuf[(r0q + 3) * 512 + col] = f2bf(accO[dc][3] * lv3);
  }
}

extern "C" void kernel_launch(void* const* d_in, const int* in_sizes, int n_in,
                              void* d_out, int out_size, void* d_ws, size_t ws_size,
                              hipStream_t stream) {
  const float* q  = (const float*)d_in[0];
  const float* k  = (const float*)d_in[1];
  const float* v  = (const float*)d_in[2];
  const int* mask = (const int*)d_in[3];
  const float* Wq = (const float*)d_in[4];
  const float* Wk = (const float*)d_in[5];
  const float* Wv = (const float*)d_in[6];
  const float* Wo = (const float*)d_in[7];
  float* out = (float*)d_out;

  char* ws = (char*)d_ws;
  const size_t SA = (size_t)8192 * 512 * 2;   // 8 MB
  unsigned short* qbf  = (unsigned short*)(ws);
  unsigned short* kbf  = (unsigned short*)(ws + SA);
  unsigned short* vbf  = (unsigned short*)(ws + 2 * SA);
  unsigned short* qkvh = (unsigned short*)(ws + 3 * SA);          // 24 MB
  unsigned short* wAll = (unsigned short*)(ws + 6 * SA);          // 2 MB
  unsigned short* woT  = wAll + (size_t)3 * 512 * 512;
  unsigned short* vtb  = qbf;  // dead after gemm_qkv
  unsigned short* ob   = kbf;  // dead after gemm_qkv

  dim3 cg(2048, 3);
  cvt3<<<cg, 256, 0, stream>>>(q, k, v, qbf, kbf, vbf);
  dim3 wg(8, 8, 4);
  wtrans4<<<wg, 256, 0, stream>>>(Wq, Wk, Wv, Wo, wAll);
  const float qscale = 0.125f * 1.44269504f;  // 1/sqrt(64) * log2(e)
  dim3 gq(64, 24);
  gemm_qkv<<<gq, 256, 0, stream>>>(qbf, kbf, vbf, wAll, qkvh, qscale);
  dim3 vg(64, 16);
  vtrans<<<vg, 256, 0, stream>>>(qkvh, vtb);
  dim3 ag(32, 8, 2);
  attn<<<ag, 512, 0, stream>>>(qkvh, vtb, mask, ob);
  dim3 go(64, 8);
  gemm_o<<<go, 256, 0, stream>>>(ob, woT, out);
}